// Round 3
// baseline (609.100 us; speedup 1.0000x reference)
//
#include <hip/hip_runtime.h>
#include <hip/hip_fp16.h>

#define I_DIM 1152
#define B_DIM 64
#define J_DIM 64
#define D_DIM 32
#define K_DIM 64
#define JD    2048   // J*D
#define ICHUNK 16
#define NCHUNK 72    // I_DIM / ICHUNK
#define G_I   18     // i's per k1 block
#define NGRP  (I_DIM / G_I)   // 64 i-groups

typedef _Float16 half8 __attribute__((ext_vector_type(8)));
typedef float f32x4 __attribute__((ext_vector_type(4)));

// -----------------------------------------------------------------------------
// K0: pre-split x (f32) into fp16 hi + lo residual arrays. ~19 MB, one-shot.
// -----------------------------------------------------------------------------
__global__ __launch_bounds__(256) void k0_split(
    const float* __restrict__ x, _Float16* __restrict__ xh,
    _Float16* __restrict__ xl) {
  const size_t t = (size_t)blockIdx.x * 256 + threadIdx.x;  // one half8 per thread
  const float4 f0 = ((const float4*)x)[t * 2];
  const float4 f1 = ((const float4*)x)[t * 2 + 1];
  const float f[8] = {f0.x, f0.y, f0.z, f0.w, f1.x, f1.y, f1.z, f1.w};
  half8 h, l;
  #pragma unroll
  for (int e = 0; e < 8; ++e) {
    _Float16 hh = (_Float16)f[e];
    h[e] = hh;
    l[e] = (_Float16)(f[e] - (float)hh);
  }
  ((half8*)xh)[t] = h;
  ((half8*)xl)[t] = l;
}

// -----------------------------------------------------------------------------
// K1 (MFMA): u_hat[b][i][jd] fp16 = sum_k W[i][jd][k] * x[b][i][k]
// u = xh*wh + xh*wl + xl*wh  (split-fp16, ~2^-21 rel err).
// W raw loads double-buffered across i (static A/B buffers, unroll-2);
// x frags are pre-split fp16, raw b128 loads (L2-resident, no VALU).
// s0 partials accumulate in-register -> spart0.
// -----------------------------------------------------------------------------
__global__ __launch_bounds__(256, 2) void k1_uhat(
    const float* __restrict__ W, const _Float16* __restrict__ xh,
    const _Float16* __restrict__ xl, __half* __restrict__ uhat,
    float* __restrict__ spart0) {
  const int jdc = blockIdx.x;              // 0..31 (fast -> spreads W stream)
  const int g   = blockIdx.y;              // 0..63 i-group
  const int lane = threadIdx.x & 63;
  const int wave = threadIdx.x >> 6;
  const int col = jdc * 64 + wave * 16 + (lane & 15);  // this lane's jd
  const int kof = (lane >> 4) * 8;                     // k sub-offset

  f32x4 s0a[4];
  #pragma unroll
  for (int m = 0; m < 4; ++m) s0a[m] = (f32x4)0.f;

  float4 wA[4], wB[4];

  auto loadW = [&](int ii, float4* dst) {
    const float* p = W + ((size_t)(g * G_I + ii) * JD + col) * K_DIM + kof;
    dst[0] = *(const float4*)p;
    dst[1] = *(const float4*)(p + 4);
    dst[2] = *(const float4*)(p + 32);
    dst[3] = *(const float4*)(p + 36);
  };

  auto process = [&](int ii, const float4* wc) {
    const int i = g * G_I + ii;
    // --- batched x fragment loads (pre-split fp16, no conversion) ---
    half8 ah0[4], ah1[4], al0[4], al1[4];
    #pragma unroll
    for (int m = 0; m < 4; ++m) {
      const size_t xb = ((size_t)(m * 16 + (lane & 15)) * I_DIM + i) * K_DIM + kof;
      ah0[m] = *(const half8*)(xh + xb);
      ah1[m] = *(const half8*)(xh + xb + 32);
      al0[m] = *(const half8*)(xl + xb);
      al1[m] = *(const half8*)(xl + xb + 32);
    }
    // --- split W raw -> hi/lo fragments ---
    const float wf[16] = {wc[0].x, wc[0].y, wc[0].z, wc[0].w,
                          wc[1].x, wc[1].y, wc[1].z, wc[1].w,
                          wc[2].x, wc[2].y, wc[2].z, wc[2].w,
                          wc[3].x, wc[3].y, wc[3].z, wc[3].w};
    half8 bh0, bl0, bh1, bl1;
    #pragma unroll
    for (int e = 0; e < 8; ++e) {
      _Float16 h0 = (_Float16)wf[e];
      bh0[e] = h0; bl0[e] = (_Float16)(wf[e] - (float)h0);
      _Float16 h1 = (_Float16)wf[8 + e];
      bh1[e] = h1; bl1[e] = (_Float16)(wf[8 + e] - (float)h1);
    }
    // --- MFMA + s0 accumulate + stores ---
    #pragma unroll
    for (int m = 0; m < 4; ++m) {
      f32x4 acc = {0.f, 0.f, 0.f, 0.f};
      acc = __builtin_amdgcn_mfma_f32_16x16x32_f16(ah0[m], bh0, acc, 0, 0, 0);
      acc = __builtin_amdgcn_mfma_f32_16x16x32_f16(ah1[m], bh1, acc, 0, 0, 0);
      acc = __builtin_amdgcn_mfma_f32_16x16x32_f16(ah0[m], bl0, acc, 0, 0, 0);
      acc = __builtin_amdgcn_mfma_f32_16x16x32_f16(ah1[m], bl1, acc, 0, 0, 0);
      acc = __builtin_amdgcn_mfma_f32_16x16x32_f16(al0[m], bh0, acc, 0, 0, 0);
      acc = __builtin_amdgcn_mfma_f32_16x16x32_f16(al1[m], bh1, acc, 0, 0, 0);
      s0a[m] += acc;
      const int brow = m * 16 + ((lane >> 4) << 2);
      #pragma unroll
      for (int r = 0; r < 4; ++r)
        uhat[((size_t)(brow + r) * I_DIM + i) * JD + col] = __float2half(acc[r]);
    }
  };

  loadW(0, wA);
  #pragma unroll 1
  for (int ii = 0; ii < G_I; ii += 2) {
    loadW(ii + 1, wB);           // prefetch i+1 while computing i
    process(ii, wA);
    if (ii + 2 < G_I) loadW(ii + 2, wA);
    process(ii + 1, wB);
  }

  #pragma unroll
  for (int m = 0; m < 4; ++m) {
    const int brow = m * 16 + ((lane >> 4) << 2);
    #pragma unroll
    for (int r = 0; r < 4; ++r)
      spart0[((size_t)g * B_DIM + brow + r) * JD + col] = s0a[m][r];
  }
}

// -----------------------------------------------------------------------------
// K3b: reduce s0 partials over 64 i-groups, *1/J, squash -> v0.
// -----------------------------------------------------------------------------
__global__ __launch_bounds__(256) void k3b_s0(
    const float* __restrict__ spart0, float* __restrict__ v0) {
  const int b = blockIdx.y;
  const int jd = blockIdx.x * 256 + threadIdx.x;
  const float* p = spart0 + (size_t)b * JD + jd;
  float s = 0.f;
  #pragma unroll 8
  for (int gg = 0; gg < NGRP; ++gg) s += p[(size_t)gg * B_DIM * JD];
  s *= (1.f / 64.f);
  float n2 = s * s;
  #pragma unroll
  for (int w = 1; w < 32; w <<= 1) n2 += __shfl_xor(n2, w);
  const float sc = n2 / (1.f + n2) * rsqrtf(n2 + 1e-9f);
  v0[(size_t)b * JD + jd] = s * sc;
}

// -----------------------------------------------------------------------------
// K4: one routing pass (unchanged; already ~6 TB/s on its u_hat stream).
// -----------------------------------------------------------------------------
__global__ __launch_bounds__(64) void k4_route(
    const __half* __restrict__ uhat, const float* __restrict__ v,
    float* __restrict__ spart) {
  const int chunk = blockIdx.x;   // 0..NCHUNK-1
  const int b = blockIdx.y;       // 0..63
  const int lane = threadIdx.x;   // 0..63
  const int jq = lane >> 2;       // 0..15
  const int d0 = (lane & 3) * 8;

  float vr[4][8];
  #pragma unroll
  for (int q = 0; q < 4; ++q) {
    const float* vp = v + ((size_t)b * J_DIM + q * 16 + jq) * D_DIM + d0;
    float4 a0 = *(const float4*)vp;
    float4 a1 = *(const float4*)(vp + 4);
    vr[q][0] = a0.x; vr[q][1] = a0.y; vr[q][2] = a0.z; vr[q][3] = a0.w;
    vr[q][4] = a1.x; vr[q][5] = a1.y; vr[q][6] = a1.z; vr[q][7] = a1.w;
  }
  float sacc[4][8];
  #pragma unroll
  for (int q = 0; q < 4; ++q)
    #pragma unroll
    for (int cc = 0; cc < 8; ++cc) sacc[q][cc] = 0.f;

  for (int ii = 0; ii < ICHUNK; ++ii) {
    const int i = chunk * ICHUNK + ii;
    const __half* row = uhat + ((size_t)b * I_DIM + i) * JD;
    float ur[4][8];
    float a[4];
    #pragma unroll
    for (int q = 0; q < 4; ++q) {
      uint4 raw = *(const uint4*)&row[q * 512 + lane * 8];
      const __half* hp = (const __half*)&raw;
      float p = 0.f;
      #pragma unroll
      for (int cc = 0; cc < 8; ++cc) {
        ur[q][cc] = __half2float(hp[cc]);
        p = fmaf(ur[q][cc], vr[q][cc], p);
      }
      p += __shfl_xor(p, 1);
      p += __shfl_xor(p, 2);
      a[q] = p;  // a[b, j=q*16+jq], replicated over the quad
    }
    float m = fmaxf(fmaxf(a[0], a[1]), fmaxf(a[2], a[3]));
    #pragma unroll
    for (int w = 4; w < 64; w <<= 1) m = fmaxf(m, __shfl_xor(m, w));
    float e[4]; float es = 0.f;
    #pragma unroll
    for (int q = 0; q < 4; ++q) { e[q] = __expf(a[q] - m); es += e[q]; }
    #pragma unroll
    for (int w = 4; w < 64; w <<= 1) es += __shfl_xor(es, w);
    const float inv = 4.f / es;  // each j counted 4x in the wave sum
    #pragma unroll
    for (int q = 0; q < 4; ++q) {
      const float cj = e[q] * inv;
      #pragma unroll
      for (int cc = 0; cc < 8; ++cc)
        sacc[q][cc] = fmaf(cj, ur[q][cc], sacc[q][cc]);
    }
  }
  float* sp = spart + ((size_t)(b * NCHUNK + chunk)) * JD;
  #pragma unroll
  for (int q = 0; q < 4; ++q) {
    float* o = sp + (q * 16 + jq) * D_DIM + d0;
    *(float4*)o       = make_float4(sacc[q][0], sacc[q][1], sacc[q][2], sacc[q][3]);
    *(float4*)(o + 4) = make_float4(sacc[q][4], sacc[q][5], sacc[q][6], sacc[q][7]);
  }
}

// -----------------------------------------------------------------------------
// K5: reduce s-partials over chunks -> squash -> vout (+optional vprev sum).
// -----------------------------------------------------------------------------
__global__ __launch_bounds__(256) void k5_reduce(
    const float* __restrict__ spart, const float* __restrict__ vprev,
    float* __restrict__ vout, float* __restrict__ vsum) {
  const int b = blockIdx.y;
  const int jd = blockIdx.x * 256 + threadIdx.x;
  const float* p = spart + (size_t)b * NCHUNK * JD + jd;
  float s = 0.f;
  #pragma unroll 8
  for (int ch = 0; ch < NCHUNK; ++ch) s += p[(size_t)ch * JD];
  float n2 = s * s;
  #pragma unroll
  for (int w = 1; w < 32; w <<= 1) n2 += __shfl_xor(n2, w);
  const float sc = n2 / (1.f + n2) * rsqrtf(n2 + 1e-9f);
  const float vv = s * sc;
  vout[(size_t)b * JD + jd] = vv;
  if (vsum) vsum[(size_t)b * JD + jd] = vv + vprev[(size_t)b * JD + jd];
}

extern "C" void kernel_launch(void* const* d_in, const int* in_sizes, int n_in,
                              void* d_out, int out_size, void* d_ws, size_t ws_size,
                              hipStream_t stream) {
  const float* x = (const float*)d_in[0];   // (B, I, 1, K, 1) f32
  const float* W = (const float*)d_in[1];   // (1, I, J, D, K) f32
  float* out = (float*)d_out;               // (B, J, 1, D, 1) f32

  char* ws = (char*)d_ws;
  __half* uhat = (__half*)ws;                                   // 302 MB
  size_t off = (size_t)B_DIM * I_DIM * JD * sizeof(__half);
  float* spart = (float*)(ws + off);                            // 37.75 MB (spart0 aliases)
  off += (size_t)B_DIM * NCHUNK * JD * sizeof(float);
  float* v0 = (float*)(ws + off);   off += (size_t)B_DIM * JD * sizeof(float);
  float* v1 = (float*)(ws + off);   off += (size_t)B_DIM * JD * sizeof(float);
  float* vsum = (float*)(ws + off); off += (size_t)B_DIM * JD * sizeof(float);
  _Float16* xh = (_Float16*)(ws + off);
  off += (size_t)B_DIM * I_DIM * K_DIM * sizeof(_Float16);      // 9.4 MB
  _Float16* xl = (_Float16*)(ws + off);

  // x hi/lo pre-split
  k0_split<<<dim3(B_DIM * I_DIM * K_DIM / 8 / 256), 256, 0, stream>>>(x, xh, xl);
  // u_hat via split-fp16 MFMA, W double-buffered; s0 partials fused
  k1_uhat<<<dim3(32, NGRP), 256, 0, stream>>>(W, xh, xl, uhat, spart);
  // it 0: finish s0 reduction -> v0
  k3b_s0<<<dim3(8, B_DIM), 256, 0, stream>>>(spart, v0);
  // it 1: b1 = u.v0 -> softmax -> s1 -> v1 (and vsum = v0+v1)
  k4_route<<<dim3(NCHUNK, B_DIM), 64, 0, stream>>>(uhat, v0, spart);
  k5_reduce<<<dim3(8, B_DIM), 256, 0, stream>>>(spart, v0, v1, vsum);
  // it 2: b2 = u.(v0+v1) -> softmax -> s2 -> v2 = output
  k4_route<<<dim3(NCHUNK, B_DIM), 64, 0, stream>>>(uhat, vsum, spart);
  k5_reduce<<<dim3(8, B_DIM), 256, 0, stream>>>(spart, nullptr, out, nullptr);
}

// Round 4
// 574.095 us; speedup vs baseline: 1.0610x; 1.0610x over previous
//
#include <hip/hip_runtime.h>
#include <hip/hip_fp16.h>

#define I_DIM 1152
#define B_DIM 64
#define J_DIM 64
#define D_DIM 32
#define K_DIM 64
#define JD    2048   // J*D
#define ICHUNK 16
#define NCHUNK 72    // I_DIM / ICHUNK

typedef _Float16 half8 __attribute__((ext_vector_type(8)));
typedef float f32x4 __attribute__((ext_vector_type(4)));

// split two float4 (8 consecutive f32) into fp16 hi + lo residual
__device__ inline void split8(const float4 a, const float4 b, half8& hi, half8& lo) {
  const float f[8] = {a.x, a.y, a.z, a.w, b.x, b.y, b.z, b.w};
  #pragma unroll
  for (int e = 0; e < 8; ++e) {
    _Float16 h = (_Float16)f[e];
    hi[e] = h;
    lo[e] = (_Float16)(f[e] - (float)h);
  }
}

// -----------------------------------------------------------------------------
// K1 (MFMA): u_hat[b][i][jd] fp16 = sum_k W[i][jd][k] * x[b][i][k]
// u = xh*wh + xh*wl + xl*wh (split-fp16, ~2^-21 rel err).
// ONE BLOCK PER i: W[i] is read as a contiguous 512KB stream (double-buffered
// across col-groups); x fragments loaded+split once per block; each (b,i)
// u_hat row is written as a contiguous 4KB chunk -> DRAM-page friendly.
// Wave w owns cols [w*512, w*512+512) = 32 col-groups of 16.
// -----------------------------------------------------------------------------
__global__ __launch_bounds__(256, 3) void k1_uhat(
    const float* __restrict__ x, const float* __restrict__ W,
    __half* __restrict__ uhat) {
  const int i = blockIdx.x;                // 0..1151
  const int lane = threadIdx.x & 63;
  const int wave = threadIdx.x >> 6;
  const int kof = (lane >> 4) * 8;         // k sub-offset (A/B frag layout)

  // ---- x fragments: load f32 + split once per block ----
  half8 ah0[4], ah1[4], al0[4], al1[4];
  #pragma unroll
  for (int m = 0; m < 4; ++m) {
    const float* xr = x + ((size_t)(m * 16 + (lane & 15)) * I_DIM + i) * K_DIM + kof;
    split8(*(const float4*)xr,        *(const float4*)(xr + 4),  ah0[m], al0[m]);
    split8(*(const float4*)(xr + 32), *(const float4*)(xr + 36), ah1[m], al1[m]);
  }

  float4 wA[4], wB[4];
  auto loadW = [&](int cg, float4* dst) {
    const int col = wave * 512 + cg * 16 + (lane & 15);
    const float* p = W + ((size_t)i * JD + col) * K_DIM + kof;
    dst[0] = *(const float4*)p;
    dst[1] = *(const float4*)(p + 4);
    dst[2] = *(const float4*)(p + 32);
    dst[3] = *(const float4*)(p + 36);
  };

  auto process = [&](int cg, const float4* wc) {
    const int col = wave * 512 + cg * 16 + (lane & 15);
    half8 bh0, bl0, bh1, bl1;
    split8(wc[0], wc[1], bh0, bl0);
    split8(wc[2], wc[3], bh1, bl1);
    #pragma unroll
    for (int m = 0; m < 4; ++m) {
      f32x4 acc = {0.f, 0.f, 0.f, 0.f};
      acc = __builtin_amdgcn_mfma_f32_16x16x32_f16(ah0[m], bh0, acc, 0, 0, 0);
      acc = __builtin_amdgcn_mfma_f32_16x16x32_f16(ah1[m], bh1, acc, 0, 0, 0);
      acc = __builtin_amdgcn_mfma_f32_16x16x32_f16(ah0[m], bl0, acc, 0, 0, 0);
      acc = __builtin_amdgcn_mfma_f32_16x16x32_f16(ah1[m], bl1, acc, 0, 0, 0);
      acc = __builtin_amdgcn_mfma_f32_16x16x32_f16(al0[m], bh0, acc, 0, 0, 0);
      acc = __builtin_amdgcn_mfma_f32_16x16x32_f16(al1[m], bh1, acc, 0, 0, 0);
      const int brow = m * 16 + ((lane >> 4) << 2);
      #pragma unroll
      for (int r = 0; r < 4; ++r)
        uhat[((size_t)(brow + r) * I_DIM + i) * JD + col] = __float2half(acc[r]);
    }
  };

  loadW(0, wA);
  #pragma unroll 1
  for (int cg = 0; cg < 32; cg += 2) {
    loadW(cg + 1, wB);                 // prefetch next col-group
    process(cg, wA);
    if (cg + 2 < 32) loadW(cg + 2, wA);
    process(cg + 1, wB);
  }
}

// -----------------------------------------------------------------------------
// K3: s0 = (1/J) * sum_i u_hat -> squash -> v0. Streaming column sum.
// grid (4, B): thread owns 2 jd (half2 loads); squash over 16-lane groups.
// -----------------------------------------------------------------------------
__global__ __launch_bounds__(256) void k3_s0(
    const __half* __restrict__ uhat, float* __restrict__ v0) {
  const int b = blockIdx.y;
  const int jd = blockIdx.x * 512 + threadIdx.x * 2;
  const __half* p = uhat + (size_t)b * I_DIM * JD + jd;
  float s0 = 0.f, s1 = 0.f;
  #pragma unroll 16
  for (int i = 0; i < I_DIM; ++i) {
    const __half2 h = *(const __half2*)(p + (size_t)i * JD);
    s0 += __low2float(h);
    s1 += __high2float(h);
  }
  s0 *= (1.f / 64.f);
  s1 *= (1.f / 64.f);
  // squash: n2 over the 32 d's of this j = 16 consecutive lanes
  float n2 = s0 * s0 + s1 * s1;
  #pragma unroll
  for (int w = 1; w < 16; w <<= 1) n2 += __shfl_xor(n2, w);
  const float sc = n2 / (1.f + n2) * rsqrtf(n2 + 1e-9f);
  float* o = v0 + (size_t)b * JD + jd;
  o[0] = s0 * sc;
  o[1] = s1 * sc;
}

// -----------------------------------------------------------------------------
// K4: one routing pass. For each (b,i): a_j = <u_hat[b,i,j,:], v[b,j,:]>,
// c = softmax_j(a), s_partial[j,d] += c_j * u_hat. One wave per (b, i-chunk).
// -----------------------------------------------------------------------------
__global__ __launch_bounds__(64) void k4_route(
    const __half* __restrict__ uhat, const float* __restrict__ v,
    float* __restrict__ spart) {
  const int chunk = blockIdx.x;   // 0..NCHUNK-1
  const int b = blockIdx.y;       // 0..63
  const int lane = threadIdx.x;   // 0..63
  const int jq = lane >> 2;       // 0..15
  const int d0 = (lane & 3) * 8;

  float vr[4][8];
  #pragma unroll
  for (int q = 0; q < 4; ++q) {
    const float* vp = v + ((size_t)b * J_DIM + q * 16 + jq) * D_DIM + d0;
    float4 a0 = *(const float4*)vp;
    float4 a1 = *(const float4*)(vp + 4);
    vr[q][0] = a0.x; vr[q][1] = a0.y; vr[q][2] = a0.z; vr[q][3] = a0.w;
    vr[q][4] = a1.x; vr[q][5] = a1.y; vr[q][6] = a1.z; vr[q][7] = a1.w;
  }
  float sacc[4][8];
  #pragma unroll
  for (int q = 0; q < 4; ++q)
    #pragma unroll
    for (int cc = 0; cc < 8; ++cc) sacc[q][cc] = 0.f;

  for (int ii = 0; ii < ICHUNK; ++ii) {
    const int i = chunk * ICHUNK + ii;
    const __half* row = uhat + ((size_t)b * I_DIM + i) * JD;
    float ur[4][8];
    float a[4];
    #pragma unroll
    for (int q = 0; q < 4; ++q) {
      uint4 raw = *(const uint4*)&row[q * 512 + lane * 8];
      const __half* hp = (const __half*)&raw;
      float p = 0.f;
      #pragma unroll
      for (int cc = 0; cc < 8; ++cc) {
        ur[q][cc] = __half2float(hp[cc]);
        p = fmaf(ur[q][cc], vr[q][cc], p);
      }
      p += __shfl_xor(p, 1);
      p += __shfl_xor(p, 2);
      a[q] = p;  // a[b, j=q*16+jq], replicated over the quad
    }
    float m = fmaxf(fmaxf(a[0], a[1]), fmaxf(a[2], a[3]));
    #pragma unroll
    for (int w = 4; w < 64; w <<= 1) m = fmaxf(m, __shfl_xor(m, w));
    float e[4]; float es = 0.f;
    #pragma unroll
    for (int q = 0; q < 4; ++q) { e[q] = __expf(a[q] - m); es += e[q]; }
    #pragma unroll
    for (int w = 4; w < 64; w <<= 1) es += __shfl_xor(es, w);
    const float inv = 4.f / es;  // each j counted 4x in the wave sum
    #pragma unroll
    for (int q = 0; q < 4; ++q) {
      const float cj = e[q] * inv;
      #pragma unroll
      for (int cc = 0; cc < 8; ++cc)
        sacc[q][cc] = fmaf(cj, ur[q][cc], sacc[q][cc]);
    }
  }
  float* sp = spart + ((size_t)(b * NCHUNK + chunk)) * JD;
  #pragma unroll
  for (int q = 0; q < 4; ++q) {
    float* o = sp + (q * 16 + jq) * D_DIM + d0;
    *(float4*)o       = make_float4(sacc[q][0], sacc[q][1], sacc[q][2], sacc[q][3]);
    *(float4*)(o + 4) = make_float4(sacc[q][4], sacc[q][5], sacc[q][6], sacc[q][7]);
  }
}

// -----------------------------------------------------------------------------
// K5: reduce s-partials over chunks -> squash -> vout (+optional vprev sum).
// -----------------------------------------------------------------------------
__global__ __launch_bounds__(256) void k5_reduce(
    const float* __restrict__ spart, const float* __restrict__ vprev,
    float* __restrict__ vout, float* __restrict__ vsum) {
  const int b = blockIdx.y;
  const int jd = blockIdx.x * 256 + threadIdx.x;
  const float* p = spart + (size_t)b * NCHUNK * JD + jd;
  float s = 0.f;
  #pragma unroll 8
  for (int ch = 0; ch < NCHUNK; ++ch) s += p[(size_t)ch * JD];
  float n2 = s * s;
  #pragma unroll
  for (int w = 1; w < 32; w <<= 1) n2 += __shfl_xor(n2, w);
  const float sc = n2 / (1.f + n2) * rsqrtf(n2 + 1e-9f);
  const float vv = s * sc;
  vout[(size_t)b * JD + jd] = vv;
  if (vsum) vsum[(size_t)b * JD + jd] = vv + vprev[(size_t)b * JD + jd];
}

extern "C" void kernel_launch(void* const* d_in, const int* in_sizes, int n_in,
                              void* d_out, int out_size, void* d_ws, size_t ws_size,
                              hipStream_t stream) {
  const float* x = (const float*)d_in[0];   // (B, I, 1, K, 1) f32
  const float* W = (const float*)d_in[1];   // (1, I, J, D, K) f32
  float* out = (float*)d_out;               // (B, J, 1, D, 1) f32

  char* ws = (char*)d_ws;
  __half* uhat = (__half*)ws;                                   // 302 MB
  size_t off = (size_t)B_DIM * I_DIM * JD * sizeof(__half);
  float* spart = (float*)(ws + off);                            // 37.75 MB
  off += (size_t)B_DIM * NCHUNK * JD * sizeof(float);
  float* v0 = (float*)(ws + off);   off += (size_t)B_DIM * JD * sizeof(float);
  float* v1 = (float*)(ws + off);   off += (size_t)B_DIM * JD * sizeof(float);
  float* vsum = (float*)(ws + off);

  // u_hat via split-fp16 MFMA; one block per i -> streaming W + 4KB store chunks
  k1_uhat<<<I_DIM, 256, 0, stream>>>(x, W, uhat);
  // it 0: s0 = mean_i u_hat -> v0
  k3_s0<<<dim3(4, B_DIM), 256, 0, stream>>>(uhat, v0);
  // it 1: b1 = u.v0 -> softmax -> s1 -> v1 (and vsum = v0+v1)
  k4_route<<<dim3(NCHUNK, B_DIM), 64, 0, stream>>>(uhat, v0, spart);
  k5_reduce<<<dim3(8, B_DIM), 256, 0, stream>>>(spart, v0, v1, vsum);
  // it 2: b2 = u.(v0+v1) -> softmax -> s2 -> v2 = output
  k4_route<<<dim3(NCHUNK, B_DIM), 64, 0, stream>>>(uhat, vsum, spart);
  k5_reduce<<<dim3(8, B_DIM), 256, 0, stream>>>(spart, nullptr, out, nullptr);
}

// Round 5
// 543.071 us; speedup vs baseline: 1.1216x; 1.0571x over previous
//
#include <hip/hip_runtime.h>
#include <hip/hip_fp16.h>

#define I_DIM 1152
#define B_DIM 64
#define J_DIM 64
#define D_DIM 32
#define K_DIM 64
#define JD    2048   // J*D
#define ICHUNK 16
#define NCHUNK 72    // I_DIM / ICHUNK

typedef _Float16 half8 __attribute__((ext_vector_type(8)));
typedef _Float16 half4 __attribute__((ext_vector_type(4)));
typedef float f32x4 __attribute__((ext_vector_type(4)));

// split two float4 (8 consecutive f32) into fp16 hi + lo residual
__device__ inline void split8(const float4 a, const float4 b, half8& hi, half8& lo) {
  const float f[8] = {a.x, a.y, a.z, a.w, b.x, b.y, b.z, b.w};
  #pragma unroll
  for (int e = 0; e < 8; ++e) {
    _Float16 h = (_Float16)f[e];
    hi[e] = h;
    lo[e] = (_Float16)(f[e] - (float)h);
  }
}

// -----------------------------------------------------------------------------
// K1 (MFMA): u_hat[i][b][jd] fp16 = sum_k W[i][jd][k] * x[b][i][k]
// u = wh*xh + wh*xl + wl*xh (split-fp16, ~2^-21 rel err).
// A = W (M=jd), B = x (N=b)  =>  D: row=(lane>>4)*4+r = jd, col=lane&15 = b.
// The 4 acc regs are 4 CONSECUTIVE jd for one b -> one packed 8B half4 store.
// u_hat layout [i][b][jd]: each block-per-i writes a dense 256KB region
// (b-stride 4KB). W streamed contiguously, 4-deep static prefetch.
// -----------------------------------------------------------------------------
__global__ __launch_bounds__(256, 3) void k1_uhat(
    const float* __restrict__ x, const float* __restrict__ W,
    __half* __restrict__ uhat) {
  const int i = blockIdx.x;                // 0..1151
  const int lane = threadIdx.x & 63;
  const int wave = threadIdx.x >> 6;
  const int kof = (lane >> 4) * 8;         // k sub-offset (frag layout)

  // ---- x fragments (B-operand: col b = m*16 + (lane&15)), split once ----
  half8 xh0[4], xh1[4], xl0[4], xl1[4];
  #pragma unroll
  for (int m = 0; m < 4; ++m) {
    const float* xr = x + ((size_t)(m * 16 + (lane & 15)) * I_DIM + i) * K_DIM + kof;
    split8(*(const float4*)xr,        *(const float4*)(xr + 4),  xh0[m], xl0[m]);
    split8(*(const float4*)(xr + 32), *(const float4*)(xr + 36), xh1[m], xl1[m]);
  }

  float4 w0[4], w1[4], w2[4], w3[4];
  auto loadW = [&](int cg, float4* dst) {
    const int row = wave * 512 + cg * 16 + (lane & 15);     // jd row (A-operand)
    const float* p = W + ((size_t)i * JD + row) * K_DIM + kof;
    dst[0] = *(const float4*)p;
    dst[1] = *(const float4*)(p + 4);
    dst[2] = *(const float4*)(p + 32);
    dst[3] = *(const float4*)(p + 36);
  };

  auto process = [&](int cg, const float4* wc) {
    half8 wh0, wl0, wh1, wl1;
    split8(wc[0], wc[1], wh0, wl0);
    split8(wc[2], wc[3], wh1, wl1);
    const int jdr = wave * 512 + cg * 16 + ((lane >> 4) << 2);  // jd of reg 0
    #pragma unroll
    for (int m = 0; m < 4; ++m) {
      f32x4 acc = {0.f, 0.f, 0.f, 0.f};
      acc = __builtin_amdgcn_mfma_f32_16x16x32_f16(wh0, xh0[m], acc, 0, 0, 0);
      acc = __builtin_amdgcn_mfma_f32_16x16x32_f16(wh1, xh1[m], acc, 0, 0, 0);
      acc = __builtin_amdgcn_mfma_f32_16x16x32_f16(wh0, xl0[m], acc, 0, 0, 0);
      acc = __builtin_amdgcn_mfma_f32_16x16x32_f16(wh1, xl1[m], acc, 0, 0, 0);
      acc = __builtin_amdgcn_mfma_f32_16x16x32_f16(wl0, xh0[m], acc, 0, 0, 0);
      acc = __builtin_amdgcn_mfma_f32_16x16x32_f16(wl1, xh1[m], acc, 0, 0, 0);
      const int b = m * 16 + (lane & 15);
      half4 o;
      #pragma unroll
      for (int r = 0; r < 4; ++r) o[r] = (_Float16)acc[r];
      *(half4*)(uhat + ((size_t)i * B_DIM + b) * JD + jdr) = o;
    }
  };

  loadW(0, w0); loadW(1, w1); loadW(2, w2); loadW(3, w3);
  #pragma unroll 1
  for (int cg = 0; cg < 32; cg += 4) {
    process(cg + 0, w0); if (cg + 4 < 32) loadW(cg + 4, w0);
    process(cg + 1, w1); if (cg + 5 < 32) loadW(cg + 5, w1);
    process(cg + 2, w2); if (cg + 6 < 32) loadW(cg + 6, w2);
    process(cg + 3, w3); if (cg + 7 < 32) loadW(cg + 7, w3);
  }
}

// -----------------------------------------------------------------------------
// K3: s0 = (1/J) * sum_i u_hat -> squash -> v0.  u_hat layout [i][b][jd].
// grid (4, B): thread owns 2 jd (half2 loads); squash over 16-lane groups.
// -----------------------------------------------------------------------------
__global__ __launch_bounds__(256) void k3_s0(
    const __half* __restrict__ uhat, float* __restrict__ v0) {
  const int b = blockIdx.y;
  const int jd = blockIdx.x * 512 + threadIdx.x * 2;
  const __half* p = uhat + (size_t)b * JD + jd;
  float s0 = 0.f, s1 = 0.f;
  #pragma unroll 16
  for (int i = 0; i < I_DIM; ++i) {
    const __half2 h = *(const __half2*)(p + (size_t)i * B_DIM * JD);
    s0 += __low2float(h);
    s1 += __high2float(h);
  }
  s0 *= (1.f / 64.f);
  s1 *= (1.f / 64.f);
  float n2 = s0 * s0 + s1 * s1;
  #pragma unroll
  for (int w = 1; w < 16; w <<= 1) n2 += __shfl_xor(n2, w);
  const float sc = n2 / (1.f + n2) * rsqrtf(n2 + 1e-9f);
  float* o = v0 + (size_t)b * JD + jd;
  o[0] = s0 * sc;
  o[1] = s1 * sc;
}

// -----------------------------------------------------------------------------
// K4: one routing pass. u_hat row for (b,i) = uhat[(i*B + b)*JD], contiguous 4KB.
// -----------------------------------------------------------------------------
__global__ __launch_bounds__(64) void k4_route(
    const __half* __restrict__ uhat, const float* __restrict__ v,
    float* __restrict__ spart) {
  const int chunk = blockIdx.x;   // 0..NCHUNK-1
  const int b = blockIdx.y;       // 0..63
  const int lane = threadIdx.x;   // 0..63
  const int jq = lane >> 2;       // 0..15
  const int d0 = (lane & 3) * 8;

  float vr[4][8];
  #pragma unroll
  for (int q = 0; q < 4; ++q) {
    const float* vp = v + ((size_t)b * J_DIM + q * 16 + jq) * D_DIM + d0;
    float4 a0 = *(const float4*)vp;
    float4 a1 = *(const float4*)(vp + 4);
    vr[q][0] = a0.x; vr[q][1] = a0.y; vr[q][2] = a0.z; vr[q][3] = a0.w;
    vr[q][4] = a1.x; vr[q][5] = a1.y; vr[q][6] = a1.z; vr[q][7] = a1.w;
  }
  float sacc[4][8];
  #pragma unroll
  for (int q = 0; q < 4; ++q)
    #pragma unroll
    for (int cc = 0; cc < 8; ++cc) sacc[q][cc] = 0.f;

  for (int ii = 0; ii < ICHUNK; ++ii) {
    const int i = chunk * ICHUNK + ii;
    const __half* row = uhat + ((size_t)i * B_DIM + b) * JD;
    float ur[4][8];
    float a[4];
    #pragma unroll
    for (int q = 0; q < 4; ++q) {
      uint4 raw = *(const uint4*)&row[q * 512 + lane * 8];
      const __half* hp = (const __half*)&raw;
      float p = 0.f;
      #pragma unroll
      for (int cc = 0; cc < 8; ++cc) {
        ur[q][cc] = __half2float(hp[cc]);
        p = fmaf(ur[q][cc], vr[q][cc], p);
      }
      p += __shfl_xor(p, 1);
      p += __shfl_xor(p, 2);
      a[q] = p;  // a[b, j=q*16+jq], replicated over the quad
    }
    float m = fmaxf(fmaxf(a[0], a[1]), fmaxf(a[2], a[3]));
    #pragma unroll
    for (int w = 4; w < 64; w <<= 1) m = fmaxf(m, __shfl_xor(m, w));
    float e[4]; float es = 0.f;
    #pragma unroll
    for (int q = 0; q < 4; ++q) { e[q] = __expf(a[q] - m); es += e[q]; }
    #pragma unroll
    for (int w = 4; w < 64; w <<= 1) es += __shfl_xor(es, w);
    const float inv = 4.f / es;  // each j counted 4x in the wave sum
    #pragma unroll
    for (int q = 0; q < 4; ++q) {
      const float cj = e[q] * inv;
      #pragma unroll
      for (int cc = 0; cc < 8; ++cc)
        sacc[q][cc] = fmaf(cj, ur[q][cc], sacc[q][cc]);
    }
  }
  float* sp = spart + ((size_t)(b * NCHUNK + chunk)) * JD;
  #pragma unroll
  for (int q = 0; q < 4; ++q) {
    float* o = sp + (q * 16 + jq) * D_DIM + d0;
    *(float4*)o       = make_float4(sacc[q][0], sacc[q][1], sacc[q][2], sacc[q][3]);
    *(float4*)(o + 4) = make_float4(sacc[q][4], sacc[q][5], sacc[q][6], sacc[q][7]);
  }
}

// -----------------------------------------------------------------------------
// K5: reduce s-partials over chunks -> squash -> vout (+optional vprev sum).
// -----------------------------------------------------------------------------
__global__ __launch_bounds__(256) void k5_reduce(
    const float* __restrict__ spart, const float* __restrict__ vprev,
    float* __restrict__ vout, float* __restrict__ vsum) {
  const int b = blockIdx.y;
  const int jd = blockIdx.x * 256 + threadIdx.x;
  const float* p = spart + (size_t)b * NCHUNK * JD + jd;
  float s = 0.f;
  #pragma unroll 8
  for (int ch = 0; ch < NCHUNK; ++ch) s += p[(size_t)ch * JD];
  float n2 = s * s;
  #pragma unroll
  for (int w = 1; w < 32; w <<= 1) n2 += __shfl_xor(n2, w);
  const float sc = n2 / (1.f + n2) * rsqrtf(n2 + 1e-9f);
  const float vv = s * sc;
  vout[(size_t)b * JD + jd] = vv;
  if (vsum) vsum[(size_t)b * JD + jd] = vv + vprev[(size_t)b * JD + jd];
}

extern "C" void kernel_launch(void* const* d_in, const int* in_sizes, int n_in,
                              void* d_out, int out_size, void* d_ws, size_t ws_size,
                              hipStream_t stream) {
  const float* x = (const float*)d_in[0];   // (B, I, 1, K, 1) f32
  const float* W = (const float*)d_in[1];   // (1, I, J, D, K) f32
  float* out = (float*)d_out;               // (B, J, 1, D, 1) f32

  char* ws = (char*)d_ws;
  __half* uhat = (__half*)ws;                                   // 302 MB, [i][b][jd]
  size_t off = (size_t)B_DIM * I_DIM * JD * sizeof(__half);
  float* spart = (float*)(ws + off);                            // 37.75 MB
  off += (size_t)B_DIM * NCHUNK * JD * sizeof(float);
  float* v0 = (float*)(ws + off);   off += (size_t)B_DIM * JD * sizeof(float);
  float* v1 = (float*)(ws + off);   off += (size_t)B_DIM * JD * sizeof(float);
  float* vsum = (float*)(ws + off);

  // u_hat via split-fp16 MFMA; packed 8B stores into dense per-i region
  k1_uhat<<<I_DIM, 256, 0, stream>>>(x, W, uhat);
  // it 0: s0 = mean_i u_hat -> v0
  k3_s0<<<dim3(4, B_DIM), 256, 0, stream>>>(uhat, v0);
  // it 1: b1 = u.v0 -> softmax -> s1 -> v1 (and vsum = v0+v1)
  k4_route<<<dim3(NCHUNK, B_DIM), 64, 0, stream>>>(uhat, v0, spart);
  k5_reduce<<<dim3(8, B_DIM), 256, 0, stream>>>(spart, v0, v1, vsum);
  // it 2: b2 = u.(v0+v1) -> softmax -> s2 -> v2 = output
  k4_route<<<dim3(NCHUNK, B_DIM), 64, 0, stream>>>(uhat, vsum, spart);
  k5_reduce<<<dim3(8, B_DIM), 256, 0, stream>>>(spart, nullptr, out, nullptr);
}

// Round 6
// 405.770 us; speedup vs baseline: 1.5011x; 1.3384x over previous
//
#include <hip/hip_runtime.h>
#include <hip/hip_fp16.h>

#define I_DIM 1152
#define B_DIM 64
#define J_DIM 64
#define D_DIM 32
#define K_DIM 64
#define JD    2048   // J*D
#define ICHUNK 16
#define NCHUNK 72    // I_DIM / ICHUNK

typedef _Float16 half8 __attribute__((ext_vector_type(8)));
typedef _Float16 half4 __attribute__((ext_vector_type(4)));
typedef float f32x4 __attribute__((ext_vector_type(4)));

// split two float4 (8 consecutive f32) into fp16 hi + lo residual
__device__ inline void split8(const float4 a, const float4 b, half8& hi, half8& lo) {
  const float f[8] = {a.x, a.y, a.z, a.w, b.x, b.y, b.z, b.w};
  #pragma unroll
  for (int e = 0; e < 8; ++e) {
    _Float16 h = (_Float16)f[e];
    hi[e] = h;
    lo[e] = (_Float16)(f[e] - (float)h);
  }
}

// -----------------------------------------------------------------------------
// K1 (MFMA): u_hat[i][b][jd] fp16 = sum_k W[i][jd][k] * x[b][i][k]
// u = wh*xh + wh*xl + wl*xh (split-fp16, ~2^-21 rel err).
// A = W (M=jd), B = x (N=b); D: row=(lane>>4)*4+r = jd, col=lane&15 = b.
// STORE PATH (new): per-wave private 8KB LDS tile [64 b][64 jd] fp16,
// XOR-swizzled in 8B chunks (phys_chunk = chunk ^ ((b&7)<<1)) so ds_write is
// ~2-way (free) and ds_read_b128 is conflict-free. Every 4 col-groups the
// tile is burst to global as 8 x 1KB instructions = 8 rows x 128B dense,
// replacing 16-row x 32B x 4KB-stride scatter (DRAM-page thrash, partial-line
// flushes -> WRITE_SIZE +40%, 2.1 TB/s ceiling).
// -----------------------------------------------------------------------------
__global__ __launch_bounds__(256, 3) void k1_uhat(
    const float* __restrict__ x, const float* __restrict__ W,
    __half* __restrict__ uhat) {
  __shared__ __half tile[4 * 64 * 64];     // 4 waves x 8KB, wave-private
  const int i = blockIdx.x;                // 0..1151
  const int lane = threadIdx.x & 63;
  const int wave = threadIdx.x >> 6;
  const int kof = (lane >> 4) * 8;         // k sub-offset (frag layout)
  char* my = (char*)(tile + wave * 64 * 64);

  // ---- x fragments (B-operand: col b = m*16 + (lane&15)), split once ----
  half8 xh0[4], xh1[4], xl0[4], xl1[4];
  #pragma unroll
  for (int m = 0; m < 4; ++m) {
    const float* xr = x + ((size_t)(m * 16 + (lane & 15)) * I_DIM + i) * K_DIM + kof;
    split8(*(const float4*)xr,        *(const float4*)(xr + 4),  xh0[m], xl0[m]);
    split8(*(const float4*)(xr + 32), *(const float4*)(xr + 36), xh1[m], xl1[m]);
  }

  float4 w0[4], w1[4], w2[4], w3[4];
  auto loadW = [&](int cg, float4* dst) {
    const int row = wave * 512 + cg * 16 + (lane & 15);     // jd row (A-operand)
    const float* p = W + ((size_t)i * JD + row) * K_DIM + kof;
    dst[0] = *(const float4*)p;
    dst[1] = *(const float4*)(p + 4);
    dst[2] = *(const float4*)(p + 32);
    dst[3] = *(const float4*)(p + 36);
  };

  auto process = [&](int cg, const float4* wc) {
    half8 wh0, wl0, wh1, wl1;
    split8(wc[0], wc[1], wh0, wl0);
    split8(wc[2], wc[3], wh1, wl1);
    const int g = lane >> 4;
    const int c = (cg & 3) * 4 + g;        // logical 8B chunk (jd_local/4)
    #pragma unroll
    for (int m = 0; m < 4; ++m) {
      f32x4 acc = {0.f, 0.f, 0.f, 0.f};
      acc = __builtin_amdgcn_mfma_f32_16x16x32_f16(wh0, xh0[m], acc, 0, 0, 0);
      acc = __builtin_amdgcn_mfma_f32_16x16x32_f16(wh1, xh1[m], acc, 0, 0, 0);
      acc = __builtin_amdgcn_mfma_f32_16x16x32_f16(wh0, xl0[m], acc, 0, 0, 0);
      acc = __builtin_amdgcn_mfma_f32_16x16x32_f16(wh1, xl1[m], acc, 0, 0, 0);
      acc = __builtin_amdgcn_mfma_f32_16x16x32_f16(wl0, xh0[m], acc, 0, 0, 0);
      acc = __builtin_amdgcn_mfma_f32_16x16x32_f16(wl1, xh1[m], acc, 0, 0, 0);
      const int b = m * 16 + (lane & 15);
      half4 o;
      #pragma unroll
      for (int r = 0; r < 4; ++r) o[r] = (_Float16)acc[r];
      // swizzled ds_write: row b (128B), phys chunk = c ^ ((b&7)<<1)
      *(half4*)(my + b * 128 + ((c ^ ((b & 7) << 1)) * 8)) = o;
    }
    if ((cg & 3) == 3) {
      // burst 8KB tile -> global: 8 instrs x (8 rows x 128B dense)
      const int jd0 = wave * 512 + (cg & ~3) * 16;   // tile's first jd
      #pragma unroll
      for (int t = 0; t < 8; ++t) {
        const int b = t * 8 + (lane >> 3);
        const int c2 = (lane & 7) * 2;               // even chunk -> 16B aligned
        const uint4 v = *(const uint4*)(my + b * 128 + ((c2 ^ ((b & 7) << 1)) * 8));
        *(uint4*)((char*)(uhat + ((size_t)i * B_DIM + b) * JD + jd0) + (lane & 7) * 16) = v;
      }
    }
  };

  loadW(0, w0); loadW(1, w1); loadW(2, w2); loadW(3, w3);
  #pragma unroll 1
  for (int cg = 0; cg < 32; cg += 4) {
    process(cg + 0, w0); if (cg + 4 < 32) loadW(cg + 4, w0);
    process(cg + 1, w1); if (cg + 5 < 32) loadW(cg + 5, w1);
    process(cg + 2, w2); if (cg + 6 < 32) loadW(cg + 6, w2);
    process(cg + 3, w3); if (cg + 7 < 32) loadW(cg + 7, w3);
  }
}

// -----------------------------------------------------------------------------
// K3: s0 = (1/J) * sum_i u_hat -> squash -> v0.  u_hat layout [i][b][jd].
// grid (4, B): thread owns 2 jd (half2 loads); squash over 16-lane groups.
// -----------------------------------------------------------------------------
__global__ __launch_bounds__(256) void k3_s0(
    const __half* __restrict__ uhat, float* __restrict__ v0) {
  const int b = blockIdx.y;
  const int jd = blockIdx.x * 512 + threadIdx.x * 2;
  const __half* p = uhat + (size_t)b * JD + jd;
  float s0 = 0.f, s1 = 0.f;
  #pragma unroll 16
  for (int i = 0; i < I_DIM; ++i) {
    const __half2 h = *(const __half2*)(p + (size_t)i * B_DIM * JD);
    s0 += __low2float(h);
    s1 += __high2float(h);
  }
  s0 *= (1.f / 64.f);
  s1 *= (1.f / 64.f);
  float n2 = s0 * s0 + s1 * s1;
  #pragma unroll
  for (int w = 1; w < 16; w <<= 1) n2 += __shfl_xor(n2, w);
  const float sc = n2 / (1.f + n2) * rsqrtf(n2 + 1e-9f);
  float* o = v0 + (size_t)b * JD + jd;
  o[0] = s0 * sc;
  o[1] = s1 * sc;
}

// -----------------------------------------------------------------------------
// K4: one routing pass. u_hat row for (b,i) = uhat[(i*B + b)*JD], contiguous 4KB.
// -----------------------------------------------------------------------------
__global__ __launch_bounds__(64) void k4_route(
    const __half* __restrict__ uhat, const float* __restrict__ v,
    float* __restrict__ spart) {
  const int chunk = blockIdx.x;   // 0..NCHUNK-1
  const int b = blockIdx.y;       // 0..63
  const int lane = threadIdx.x;   // 0..63
  const int jq = lane >> 2;       // 0..15
  const int d0 = (lane & 3) * 8;

  float vr[4][8];
  #pragma unroll
  for (int q = 0; q < 4; ++q) {
    const float* vp = v + ((size_t)b * J_DIM + q * 16 + jq) * D_DIM + d0;
    float4 a0 = *(const float4*)vp;
    float4 a1 = *(const float4*)(vp + 4);
    vr[q][0] = a0.x; vr[q][1] = a0.y; vr[q][2] = a0.z; vr[q][3] = a0.w;
    vr[q][4] = a1.x; vr[q][5] = a1.y; vr[q][6] = a1.z; vr[q][7] = a1.w;
  }
  float sacc[4][8];
  #pragma unroll
  for (int q = 0; q < 4; ++q)
    #pragma unroll
    for (int cc = 0; cc < 8; ++cc) sacc[q][cc] = 0.f;

  for (int ii = 0; ii < ICHUNK; ++ii) {
    const int i = chunk * ICHUNK + ii;
    const __half* row = uhat + ((size_t)i * B_DIM + b) * JD;
    float ur[4][8];
    float a[4];
    #pragma unroll
    for (int q = 0; q < 4; ++q) {
      uint4 raw = *(const uint4*)&row[q * 512 + lane * 8];
      const __half* hp = (const __half*)&raw;
      float p = 0.f;
      #pragma unroll
      for (int cc = 0; cc < 8; ++cc) {
        ur[q][cc] = __half2float(hp[cc]);
        p = fmaf(ur[q][cc], vr[q][cc], p);
      }
      p += __shfl_xor(p, 1);
      p += __shfl_xor(p, 2);
      a[q] = p;  // a[b, j=q*16+jq], replicated over the quad
    }
    float m = fmaxf(fmaxf(a[0], a[1]), fmaxf(a[2], a[3]));
    #pragma unroll
    for (int w = 4; w < 64; w <<= 1) m = fmaxf(m, __shfl_xor(m, w));
    float e[4]; float es = 0.f;
    #pragma unroll
    for (int q = 0; q < 4; ++q) { e[q] = __expf(a[q] - m); es += e[q]; }
    #pragma unroll
    for (int w = 4; w < 64; w <<= 1) es += __shfl_xor(es, w);
    const float inv = 4.f / es;  // each j counted 4x in the wave sum
    #pragma unroll
    for (int q = 0; q < 4; ++q) {
      const float cj = e[q] * inv;
      #pragma unroll
      for (int cc = 0; cc < 8; ++cc)
        sacc[q][cc] = fmaf(cj, ur[q][cc], sacc[q][cc]);
    }
  }
  float* sp = spart + ((size_t)(b * NCHUNK + chunk)) * JD;
  #pragma unroll
  for (int q = 0; q < 4; ++q) {
    float* o = sp + (q * 16 + jq) * D_DIM + d0;
    *(float4*)o       = make_float4(sacc[q][0], sacc[q][1], sacc[q][2], sacc[q][3]);
    *(float4*)(o + 4) = make_float4(sacc[q][4], sacc[q][5], sacc[q][6], sacc[q][7]);
  }
}

// -----------------------------------------------------------------------------
// K5: reduce s-partials over chunks -> squash -> vout (+optional vprev sum).
// -----------------------------------------------------------------------------
__global__ __launch_bounds__(256) void k5_reduce(
    const float* __restrict__ spart, const float* __restrict__ vprev,
    float* __restrict__ vout, float* __restrict__ vsum) {
  const int b = blockIdx.y;
  const int jd = blockIdx.x * 256 + threadIdx.x;
  const float* p = spart + (size_t)b * NCHUNK * JD + jd;
  float s = 0.f;
  #pragma unroll 8
  for (int ch = 0; ch < NCHUNK; ++ch) s += p[(size_t)ch * JD];
  float n2 = s * s;
  #pragma unroll
  for (int w = 1; w < 32; w <<= 1) n2 += __shfl_xor(n2, w);
  const float sc = n2 / (1.f + n2) * rsqrtf(n2 + 1e-9f);
  const float vv = s * sc;
  vout[(size_t)b * JD + jd] = vv;
  if (vsum) vsum[(size_t)b * JD + jd] = vv + vprev[(size_t)b * JD + jd];
}

extern "C" void kernel_launch(void* const* d_in, const int* in_sizes, int n_in,
                              void* d_out, int out_size, void* d_ws, size_t ws_size,
                              hipStream_t stream) {
  const float* x = (const float*)d_in[0];   // (B, I, 1, K, 1) f32
  const float* W = (const float*)d_in[1];   // (1, I, J, D, K) f32
  float* out = (float*)d_out;               // (B, J, 1, D, 1) f32

  char* ws = (char*)d_ws;
  __half* uhat = (__half*)ws;                                   // 302 MB, [i][b][jd]
  size_t off = (size_t)B_DIM * I_DIM * JD * sizeof(__half);
  float* spart = (float*)(ws + off);                            // 37.75 MB
  off += (size_t)B_DIM * NCHUNK * JD * sizeof(float);
  float* v0 = (float*)(ws + off);   off += (size_t)B_DIM * JD * sizeof(float);
  float* v1 = (float*)(ws + off);   off += (size_t)B_DIM * JD * sizeof(float);
  float* vsum = (float*)(ws + off);

  // u_hat via split-fp16 MFMA; LDS-staged dense 1KB burst stores
  k1_uhat<<<I_DIM, 256, 0, stream>>>(x, W, uhat);
  // it 0: s0 = mean_i u_hat -> v0
  k3_s0<<<dim3(4, B_DIM), 256, 0, stream>>>(uhat, v0);
  // it 1: b1 = u.v0 -> softmax -> s1 -> v1 (and vsum = v0+v1)
  k4_route<<<dim3(NCHUNK, B_DIM), 64, 0, stream>>>(uhat, v0, spart);
  k5_reduce<<<dim3(8, B_DIM), 256, 0, stream>>>(spart, v0, v1, vsum);
  // it 2: b2 = u.(v0+v1) -> softmax -> s2 -> v2 = output
  k4_route<<<dim3(NCHUNK, B_DIM), 64, 0, stream>>>(uhat, vsum, spart);
  k5_reduce<<<dim3(8, B_DIM), 256, 0, stream>>>(spart, nullptr, out, nullptr);
}